// Round 10
// baseline (3950.594 us; speedup 1.0000x reference)
//
#include <hip/hip_runtime.h>
#include <math.h>

// VQ quantizer: z [65536, 256] fp32, codebook [1024, 256] fp32.
// Outputs flat: z_q [16777216] | loss [1] | indices [65536] (as float values).
//
// Numerics contract (validated R1/R4/R5/R8/R9, absmax 0.0 — keep bit-identical):
//   A_t = sum(z_t^2)  -- numpy pairwise order (8-acc chains, 128-blocks, fixed tree)
//   B_n = sum(e_n^2)  -- same
//   d   = fl( fl(A+B) - 2*M ),  M = fp32 fma-accumulated dot, k ascending
//   argmin: global first-min == lexicographic min of key (d_bits<<32 | idx)
//   z_q_out = fl( z + fl(e - z) ),  loss = fl(mf + fl(10*mf)), mf=(float)(Σdx²/2^24)
//
// R8: 4x8 tile, VGPR=60, 16 waves -> issue-bound (50% non-FMA slots), 435 us.
// R9: 8x8 tile, VGPR=152, ~1 block/CU -> latency-bound (VALU 57%), 749 us.
// R10: 8x8 tile + global_load_lds direct DMA staging (no staging VGPRs, no
// transpose writes), row-major LDS with source-side 16B-block swizzle
// (phys = blk ^ ((row>>2)&7)), e-rows loaded in halves -> ~112 live regs,
// __launch_bounds__(256,4) caps at 128 -> 4 blocks/CU.

#define NTOK     65536
#define DDIM     256
#define NCODE    1024
#define LOSS_OFF 16777216
#define IDX_OFF  16777217

// ws layout: [0] double loss_acc | [64] float wsB[1024] | [8192] u64 keys[65536]
//            | [532480] float wsA[65536]

#define GLOAD_LDS16(gp, lp)                                                       \
    __builtin_amdgcn_global_load_lds(                                             \
        (const __attribute__((address_space(1))) void*)(gp),                      \
        (__attribute__((address_space(3))) void*)(lp), 16, 0, 0)

// ---------------- kernel 0: B_n (numpy-pairwise), zero loss, init argmin keys.
__global__ void vq_prep(const float* __restrict__ cb, float* __restrict__ wsB,
                        double* __restrict__ loss_acc,
                        unsigned long long* __restrict__ keys)
{
#pragma clang fp contract(off)
    int gid = blockIdx.x * blockDim.x + threadIdx.x;
    if (gid == 0) *loss_acc = 0.0;
    unsigned long long* kp = keys + (size_t)gid * 4;
    kp[0] = kp[1] = kp[2] = kp[3] = 0xFFFFFFFFFFFFFFFFull;
    if (gid >= NCODE) return;
    const float* a = cb + gid * DDIM;
    float half[2];
    for (int h = 0; h < 2; ++h) {
        const float* b = a + h * 128;
        float r[8];
#pragma unroll
        for (int j = 0; j < 8; ++j) { float v = b[j]; r[j] = v * v; }
        for (int i = 8; i < 128; i += 8) {
#pragma unroll
            for (int j = 0; j < 8; ++j) { float v = b[i + j]; float s = v * v; r[j] = r[j] + s; }
        }
        half[h] = ((r[0] + r[1]) + (r[2] + r[3])) + ((r[4] + r[5]) + (r[6] + r[7]));
    }
    wsB[gid] = half[0] + half[1];
}

// ---------------- kernel 0b: A_t (numpy-pairwise) for every token.
__global__ void vq_anorm(const float* __restrict__ z, float* __restrict__ wsA)
{
#pragma clang fp contract(off)
    int t = blockIdx.x * blockDim.x + threadIdx.x;
    const float* a = z + (size_t)t * DDIM;
    float half[2];
    for (int h = 0; h < 2; ++h) {
        const float* b = a + h * 128;
        float r[8];
#pragma unroll
        for (int j = 0; j < 8; ++j) { float v = b[j]; r[j] = v * v; }
        for (int i = 8; i < 128; i += 8) {
#pragma unroll
            for (int j = 0; j < 8; ++j) { float v = b[i + j]; float s = v * v; r[j] = r[j] + s; }
        }
        half[h] = ((r[0] + r[1]) + (r[2] + r[3])) + ((r[4] + r[5]) + (r[6] + r[7]));
    }
    wsA[t] = half[0] + half[1];
}

// ---------------- kernel 1: distance GEMM + per-tile argmin -> atomicMin keys.
// Grid 4096 x 256: block b -> xcd = b&7, sl = b>>3, token-tile tt = xcd*64+(sl>>3),
// code-tile ct = sl&7 (siblings of a token-tile share one XCD's L2).
// LDS tiles row-major [128 rows][32 floats], 16B blocks permuted per row:
// phys_blk p holds logical blk p ^ ((row>>2)&7). Staged by global_load_lds
// (linear dest, per-lane swizzled SOURCE address); reads apply the same XOR.
__global__ __launch_bounds__(256, 4) void vq_main(const float* __restrict__ z,
                                                  const float* __restrict__ cb,
                                                  const float* __restrict__ wsB,
                                                  const float* __restrict__ wsA,
                                                  unsigned long long* __restrict__ keys)
{
    __shared__ float zs[128 * 32];  // 16 KB, rows = tokens
    __shared__ float es[128 * 32];  // 16 KB, rows = codes
    __shared__ float Bl[128];

    const int tid = threadIdx.x;
    const int tx = tid & 15, ty = tid >> 4;      // 16x16 thread grid
    const int b = blockIdx.x;
    const int xcd = b & 7, sl = b >> 3;
    const int tt = xcd * 64 + (sl >> 3);
    const int ct = sl & 7;
    const int t0 = tt * 128;
    const int n0 = ct * 128;

    if (tid < 128) Bl[tid] = wsB[n0 + tid];

    // staging geometry: wave wv stages rows [wv*32, wv*32+32) in 4 issues of
    // 8 rows; lane L -> row += L>>3, phys blk = L&7, source blk = phys ^ swz(row)
    const int L = tid & 63;
    const int wv = tid >> 6;
    int zoff[4], eoff[4];   // per-lane global byte offsets (add kc*128 at issue)
#pragma unroll
    for (int s = 0; s < 4; ++s) {
        int row = wv * 32 + s * 8 + (L >> 3);
        int blk = (L & 7) ^ ((row >> 2) & 7);
        zoff[s] = (t0 + row) * 1024 + blk * 16;
        eoff[s] = (n0 + row) * 1024 + blk * 16;
    }

    float acc[8][8];
#pragma unroll
    for (int i = 0; i < 8; ++i)
#pragma unroll
        for (int j = 0; j < 8; ++j) acc[i][j] = 0.0f;

    const int szy = ty & 7;   // read swizzle for z rows 4ty+i and 64+4ty+i
    const int sxw = tx & 7;   // read swizzle for e rows 4tx+j and 64+4tx+j
    const char* zc = (const char*)z;
    const char* ec = (const char*)cb;

    for (int kc = 0; kc < 8; ++kc) {
        if (kc) __syncthreads();            // readers of kc-1 done before overwrite
#pragma unroll
        for (int s = 0; s < 4; ++s) {       // 8 x global_load_lds (dwordx4 DMA)
            GLOAD_LDS16(zc + (zoff[s] + kc * 128), (char*)zs + wv * 4096 + s * 1024);
            GLOAD_LDS16(ec + (eoff[s] + kc * 128), (char*)es + wv * 4096 + s * 1024);
        }
        __syncthreads();                    // vmcnt(0) drain + visibility

        // 8 blocks of 4 k-values: 20 ds_read_b128 + 256 FMA each
#pragma unroll
        for (int blk = 0; blk < 8; ++blk) {
            const int oz = ((blk ^ szy) << 2);
            const int oe = ((blk ^ sxw) << 2);
            float4 a0, a1, a2, a3, e0, e1, e2, e3;

#define FMA4(av, ev, ii, jj)                                                      \
            acc[ii][jj] = __builtin_fmaf(av.x, ev.x, acc[ii][jj]);                \
            acc[ii][jj] = __builtin_fmaf(av.y, ev.y, acc[ii][jj]);                \
            acc[ii][jj] = __builtin_fmaf(av.z, ev.z, acc[ii][jj]);                \
            acc[ii][jj] = __builtin_fmaf(av.w, ev.w, acc[ii][jj]);

            // z group 0 (tokens 4ty+i), e group 0 (codes 4tx+j)
            a0 = *(const float4*)&zs[128 * ty + 0  + oz];
            a1 = *(const float4*)&zs[128 * ty + 32 + oz];
            a2 = *(const float4*)&zs[128 * ty + 64 + oz];
            a3 = *(const float4*)&zs[128 * ty + 96 + oz];
            e0 = *(const float4*)&es[128 * tx + 0  + oe];
            e1 = *(const float4*)&es[128 * tx + 32 + oe];
            e2 = *(const float4*)&es[128 * tx + 64 + oe];
            e3 = *(const float4*)&es[128 * tx + 96 + oe];
            FMA4(a0, e0, 0, 0) FMA4(a0, e1, 0, 1) FMA4(a0, e2, 0, 2) FMA4(a0, e3, 0, 3)
            FMA4(a1, e0, 1, 0) FMA4(a1, e1, 1, 1) FMA4(a1, e2, 1, 2) FMA4(a1, e3, 1, 3)
            FMA4(a2, e0, 2, 0) FMA4(a2, e1, 2, 1) FMA4(a2, e2, 2, 2) FMA4(a2, e3, 2, 3)
            FMA4(a3, e0, 3, 0) FMA4(a3, e1, 3, 1) FMA4(a3, e2, 3, 2) FMA4(a3, e3, 3, 3)

            // e group 1 (codes 64+4tx+j)
            e0 = *(const float4*)&es[2048 + 128 * tx + 0  + oe];
            e1 = *(const float4*)&es[2048 + 128 * tx + 32 + oe];
            e2 = *(const float4*)&es[2048 + 128 * tx + 64 + oe];
            e3 = *(const float4*)&es[2048 + 128 * tx + 96 + oe];
            FMA4(a0, e0, 0, 4) FMA4(a0, e1, 0, 5) FMA4(a0, e2, 0, 6) FMA4(a0, e3, 0, 7)
            FMA4(a1, e0, 1, 4) FMA4(a1, e1, 1, 5) FMA4(a1, e2, 1, 6) FMA4(a1, e3, 1, 7)
            FMA4(a2, e0, 2, 4) FMA4(a2, e1, 2, 5) FMA4(a2, e2, 2, 6) FMA4(a2, e3, 2, 7)
            FMA4(a3, e0, 3, 4) FMA4(a3, e1, 3, 5) FMA4(a3, e2, 3, 6) FMA4(a3, e3, 3, 7)

            // z group 1 (tokens 64+4ty+i), e still group 1
            a0 = *(const float4*)&zs[2048 + 128 * ty + 0  + oz];
            a1 = *(const float4*)&zs[2048 + 128 * ty + 32 + oz];
            a2 = *(const float4*)&zs[2048 + 128 * ty + 64 + oz];
            a3 = *(const float4*)&zs[2048 + 128 * ty + 96 + oz];
            FMA4(a0, e0, 4, 4) FMA4(a0, e1, 4, 5) FMA4(a0, e2, 4, 6) FMA4(a0, e3, 4, 7)
            FMA4(a1, e0, 5, 4) FMA4(a1, e1, 5, 5) FMA4(a1, e2, 5, 6) FMA4(a1, e3, 5, 7)
            FMA4(a2, e0, 6, 4) FMA4(a2, e1, 6, 5) FMA4(a2, e2, 6, 6) FMA4(a2, e3, 6, 7)
            FMA4(a3, e0, 7, 4) FMA4(a3, e1, 7, 5) FMA4(a3, e2, 7, 6) FMA4(a3, e3, 7, 7)

            // e group 0 reload (cheaper than keeping 8 e-rows live)
            e0 = *(const float4*)&es[128 * tx + 0  + oe];
            e1 = *(const float4*)&es[128 * tx + 32 + oe];
            e2 = *(const float4*)&es[128 * tx + 64 + oe];
            e3 = *(const float4*)&es[128 * tx + 96 + oe];
            FMA4(a0, e0, 4, 0) FMA4(a0, e1, 4, 1) FMA4(a0, e2, 4, 2) FMA4(a0, e3, 4, 3)
            FMA4(a1, e0, 5, 0) FMA4(a1, e1, 5, 1) FMA4(a1, e2, 5, 2) FMA4(a1, e3, 5, 3)
            FMA4(a2, e0, 6, 0) FMA4(a2, e1, 6, 1) FMA4(a2, e2, 6, 2) FMA4(a2, e3, 6, 3)
            FMA4(a3, e0, 7, 0) FMA4(a3, e1, 7, 1) FMA4(a3, e2, 7, 2) FMA4(a3, e3, 7, 3)
#undef FMA4
        }
    }

    // epilogue: token norms (bit-identical, from vq_anorm), distances, first-min
    float Aval[8];
    {
        float4 v0 = *(const float4*)(wsA + t0 + 4 * ty);
        float4 v1 = *(const float4*)(wsA + t0 + 64 + 4 * ty);
        Aval[0] = v0.x; Aval[1] = v0.y; Aval[2] = v0.z; Aval[3] = v0.w;
        Aval[4] = v1.x; Aval[5] = v1.y; Aval[6] = v1.z; Aval[7] = v1.w;
    }

    float best[8];
    int   bidx[8];
#pragma unroll
    for (int i = 0; i < 8; ++i) { best[i] = __builtin_inff(); bidx[i] = 0x7fffffff; }
#pragma unroll
    for (int i = 0; i < 8; ++i)
#pragma unroll
        for (int j = 0; j < 8; ++j) {
            int cl = (j < 4) ? (4 * tx + j) : (64 + 4 * tx + (j - 4));
            float t1 = Aval[i] + Bl[cl];
            float dist = t1 - 2.0f * acc[i][j];
            if (dist < best[i]) { best[i] = dist; bidx[i] = n0 + cl; }
        }

    // lexicographic (d, idx) min over the 16 tx-threads per token
#pragma unroll
    for (int i = 0; i < 8; ++i) {
        float d = best[i]; int w = bidx[i];
        for (int off = 8; off; off >>= 1) {
            float od = __shfl_xor(d, off);
            int   ow = __shfl_xor(w, off);
            if (od < d || (od == d && ow < w)) { d = od; w = ow; }
        }
        best[i] = d; bidx[i] = w;
    }

    // merge across code-tiles: key = d_bits<<32 | idx (d>0 so bits are monotone)
    if (tx == 0) {
#pragma unroll
        for (int i = 0; i < 8; ++i) {
            int tl = (i < 4) ? (4 * ty + i) : (64 + 4 * ty + (i - 4));
            unsigned long long key =
                ((unsigned long long)__float_as_uint(best[i]) << 32) |
                (unsigned int)bidx[i];
            atomicMin(&keys[t0 + tl], key);
        }
    }
}

// ---------------- kernel 2: gather z_q, indices, fp64 loss partials.
__global__ __launch_bounds__(256) void vq_gather(const float* __restrict__ z,
                                                 const float* __restrict__ cb,
                                                 const unsigned long long* __restrict__ keys,
                                                 double* __restrict__ loss_acc,
                                                 float* __restrict__ out)
{
    __shared__ double lred[4];
    const int tid = threadIdx.x;
    const int tx = tid & 15, ty = tid >> 4;
    const int t0 = blockIdx.x * 64;

    double ld = 0.0;
#pragma unroll
    for (int i = 0; i < 4; ++i) {
        int t = t0 + ty * 4 + i;
        unsigned long long key = keys[t];
        int w = (int)(unsigned int)(key & 0xFFFFFFFFull);
        const float4* crow = (const float4*)(cb + (size_t)w * DDIM);
        const float4* zrow = (const float4*)(z + (size_t)t * DDIM);
        float4* orow = (float4*)(out + (size_t)t * DDIM);
#pragma unroll
        for (int q = 0; q < 4; ++q) {
            int c4 = tx * 4 + q;
            float4 e4 = crow[c4];
            float4 z4 = zrow[c4];
            float4 o;
            float dx;
            dx = e4.x - z4.x; o.x = z4.x + dx; ld += (double)(dx * dx);
            dx = e4.y - z4.y; o.y = z4.y + dx; ld += (double)(dx * dx);
            dx = e4.z - z4.z; o.z = z4.z + dx; ld += (double)(dx * dx);
            dx = e4.w - z4.w; o.w = z4.w + dx; ld += (double)(dx * dx);
            orow[c4] = o;
        }
        if (tx == 0) out[IDX_OFF + t] = (float)w;
    }

    for (int off = 32; off; off >>= 1) ld += __shfl_down(ld, off);
    int lane = tid & 63, wvv = tid >> 6;
    if (lane == 0) lred[wvv] = ld;
    __syncthreads();
    if (tid == 0) {
        double s = (lred[0] + lred[1]) + (lred[2] + lred[3]);
        atomicAdd(loss_acc, s);
    }
}

// ---------------- kernel 3: finalize loss = fl(mf + fl(10*mf))
__global__ void vq_finish(const double* __restrict__ loss_acc, float* __restrict__ out)
{
#pragma clang fp contract(off)
    double m = *loss_acc / 16777216.0;
    float mf = (float)m;
    float second = 10.0f * mf;
    out[LOSS_OFF] = mf + second;
}

extern "C" void kernel_launch(void* const* d_in, const int* in_sizes, int n_in,
                              void* d_out, int out_size, void* d_ws, size_t ws_size,
                              hipStream_t stream)
{
    (void)in_sizes; (void)n_in; (void)out_size; (void)ws_size;
    const float* z  = (const float*)d_in[0];
    const float* cb = (const float*)d_in[1];
    float* out = (float*)d_out;
    double* loss_acc = (double*)d_ws;                                      // 8 B
    float* wsB = (float*)((char*)d_ws + 64);                               // 4 KB
    unsigned long long* keys = (unsigned long long*)((char*)d_ws + 8192);  // 512 KB
    float* wsA = (float*)((char*)d_ws + 532480);                           // 256 KB

    vq_prep<<<dim3(64), dim3(256), 0, stream>>>(cb, wsB, loss_acc, keys);
    vq_anorm<<<dim3(NTOK / 256), dim3(256), 0, stream>>>(z, wsA);
    vq_main<<<dim3(4096), dim3(256), 0, stream>>>(z, cb, wsB, wsA, keys);
    vq_gather<<<dim3(NTOK / 64), dim3(256), 0, stream>>>(z, cb, keys, loss_acc, out);
    vq_finish<<<dim3(1), dim3(1), 0, stream>>>(loss_acc, out);
}

// Round 11
// 472.873 us; speedup vs baseline: 8.3544x; 8.3544x over previous
//
#include <hip/hip_runtime.h>
#include <math.h>

// VQ quantizer: z [65536, 256] fp32, codebook [1024, 256] fp32.
// Outputs flat: z_q [16777216] | loss [1] | indices [65536] (as float values).
//
// Numerics contract (validated R1/R4/R5/R8/R9/R10, absmax 0.0 — keep bit-identical):
//   A_t = sum(z_t^2)  -- numpy pairwise order (8-acc chains, 128-blocks, fixed tree)
//   B_n = sum(e_n^2)  -- same
//   d   = fl( fl(A+B) - 2*M ),  M = fp32 fma-accumulated dot, k ascending
//   argmin: global first-min == lexicographic min of key (d_bits<<32 | idx)
//   z_q_out = fl( z + fl(e - z) ),  loss = fl(mf + fl(10*mf)), mf=(float)(Σdx²/2^24)
//
// HARD RULE (R4=64, R5=64, R10=64 vs R8=60, R9=152): a second __launch_bounds__
// arg makes the allocator pin VGPR=64 and spill GBs of scratch. NEVER pass it.
// R10's DMA-staged loop never actually ran in registers; this round = R10 minus
// the ",4". Expect VGPR ~120, no spill, 4 waves/SIMD.

#define NTOK     65536
#define DDIM     256
#define NCODE    1024
#define LOSS_OFF 16777216
#define IDX_OFF  16777217

// ws layout: [0] double loss_acc | [64] float wsB[1024] | [8192] u64 keys[65536]
//            | [532480] float wsA[65536]

#define GLOAD_LDS16(gp, lp)                                                       \
    __builtin_amdgcn_global_load_lds(                                             \
        (const __attribute__((address_space(1))) void*)(gp),                      \
        (__attribute__((address_space(3))) void*)(lp), 16, 0, 0)

// ---------------- kernel 0: B_n (numpy-pairwise), zero loss, init argmin keys.
__global__ void vq_prep(const float* __restrict__ cb, float* __restrict__ wsB,
                        double* __restrict__ loss_acc,
                        unsigned long long* __restrict__ keys)
{
#pragma clang fp contract(off)
    int gid = blockIdx.x * blockDim.x + threadIdx.x;
    if (gid == 0) *loss_acc = 0.0;
    unsigned long long* kp = keys + (size_t)gid * 4;
    kp[0] = kp[1] = kp[2] = kp[3] = 0xFFFFFFFFFFFFFFFFull;
    if (gid >= NCODE) return;
    const float* a = cb + gid * DDIM;
    float half[2];
    for (int h = 0; h < 2; ++h) {
        const float* b = a + h * 128;
        float r[8];
#pragma unroll
        for (int j = 0; j < 8; ++j) { float v = b[j]; r[j] = v * v; }
        for (int i = 8; i < 128; i += 8) {
#pragma unroll
            for (int j = 0; j < 8; ++j) { float v = b[i + j]; float s = v * v; r[j] = r[j] + s; }
        }
        half[h] = ((r[0] + r[1]) + (r[2] + r[3])) + ((r[4] + r[5]) + (r[6] + r[7]));
    }
    wsB[gid] = half[0] + half[1];
}

// ---------------- kernel 0b: A_t (numpy-pairwise) for every token.
__global__ void vq_anorm(const float* __restrict__ z, float* __restrict__ wsA)
{
#pragma clang fp contract(off)
    int t = blockIdx.x * blockDim.x + threadIdx.x;
    const float* a = z + (size_t)t * DDIM;
    float half[2];
    for (int h = 0; h < 2; ++h) {
        const float* b = a + h * 128;
        float r[8];
#pragma unroll
        for (int j = 0; j < 8; ++j) { float v = b[j]; r[j] = v * v; }
        for (int i = 8; i < 128; i += 8) {
#pragma unroll
            for (int j = 0; j < 8; ++j) { float v = b[i + j]; float s = v * v; r[j] = r[j] + s; }
        }
        half[h] = ((r[0] + r[1]) + (r[2] + r[3])) + ((r[4] + r[5]) + (r[6] + r[7]));
    }
    wsA[t] = half[0] + half[1];
}

// ---------------- kernel 1: distance GEMM + per-tile argmin -> atomicMin keys.
// Grid 4096 x 256: block b -> xcd = b&7, sl = b>>3, token-tile tt = xcd*64+(sl>>3),
// code-tile ct = sl&7 (siblings of a token-tile share one XCD's L2).
// LDS tiles row-major [128 rows][32 floats], 16B blocks permuted per row:
// phys_blk p holds logical blk p ^ ((row>>2)&7). Staged by global_load_lds
// (linear dest, per-lane swizzled SOURCE address); reads apply the same XOR.
__global__ __launch_bounds__(256) void vq_main(const float* __restrict__ z,
                                               const float* __restrict__ cb,
                                               const float* __restrict__ wsB,
                                               const float* __restrict__ wsA,
                                               unsigned long long* __restrict__ keys)
{
    __shared__ float zs[128 * 32];  // 16 KB, rows = tokens
    __shared__ float es[128 * 32];  // 16 KB, rows = codes
    __shared__ float Bl[128];

    const int tid = threadIdx.x;
    const int tx = tid & 15, ty = tid >> 4;      // 16x16 thread grid
    const int b = blockIdx.x;
    const int xcd = b & 7, sl = b >> 3;
    const int tt = xcd * 64 + (sl >> 3);
    const int ct = sl & 7;
    const int t0 = tt * 128;
    const int n0 = ct * 128;

    if (tid < 128) Bl[tid] = wsB[n0 + tid];

    // staging geometry: wave wv stages rows [wv*32, wv*32+32) in 4 issues of
    // 8 rows; lane L -> row += L>>3, phys blk = L&7, source blk = phys ^ swz(row)
    const int L = tid & 63;
    const int wv = tid >> 6;
    int zoff[4], eoff[4];   // per-lane global byte offsets (add kc*128 at issue)
#pragma unroll
    for (int s = 0; s < 4; ++s) {
        int row = wv * 32 + s * 8 + (L >> 3);
        int blk = (L & 7) ^ ((row >> 2) & 7);
        zoff[s] = (t0 + row) * 1024 + blk * 16;
        eoff[s] = (n0 + row) * 1024 + blk * 16;
    }

    float acc[8][8];
#pragma unroll
    for (int i = 0; i < 8; ++i)
#pragma unroll
        for (int j = 0; j < 8; ++j) acc[i][j] = 0.0f;

    const int szy = ty & 7;   // read swizzle for z rows 4ty+i and 64+4ty+i
    const int sxw = tx & 7;   // read swizzle for e rows 4tx+j and 64+4tx+j
    const char* zc = (const char*)z;
    const char* ec = (const char*)cb;

    for (int kc = 0; kc < 8; ++kc) {
        if (kc) __syncthreads();            // readers of kc-1 done before overwrite
#pragma unroll
        for (int s = 0; s < 4; ++s) {       // 8 x global_load_lds (dwordx4 DMA)
            GLOAD_LDS16(zc + (zoff[s] + kc * 128), (char*)zs + wv * 4096 + s * 1024);
            GLOAD_LDS16(ec + (eoff[s] + kc * 128), (char*)es + wv * 4096 + s * 1024);
        }
        __syncthreads();                    // vmcnt(0) drain + visibility

        // 8 blocks of 4 k-values: 20 ds_read_b128 + 256 FMA each
#pragma unroll
        for (int blk = 0; blk < 8; ++blk) {
            const int oz = ((blk ^ szy) << 2);
            const int oe = ((blk ^ sxw) << 2);
            float4 a0, a1, a2, a3, e0, e1, e2, e3;

#define FMA4(av, ev, ii, jj)                                                      \
            acc[ii][jj] = __builtin_fmaf(av.x, ev.x, acc[ii][jj]);                \
            acc[ii][jj] = __builtin_fmaf(av.y, ev.y, acc[ii][jj]);                \
            acc[ii][jj] = __builtin_fmaf(av.z, ev.z, acc[ii][jj]);                \
            acc[ii][jj] = __builtin_fmaf(av.w, ev.w, acc[ii][jj]);

            // z group 0 (tokens 4ty+i), e group 0 (codes 4tx+j)
            a0 = *(const float4*)&zs[128 * ty + 0  + oz];
            a1 = *(const float4*)&zs[128 * ty + 32 + oz];
            a2 = *(const float4*)&zs[128 * ty + 64 + oz];
            a3 = *(const float4*)&zs[128 * ty + 96 + oz];
            e0 = *(const float4*)&es[128 * tx + 0  + oe];
            e1 = *(const float4*)&es[128 * tx + 32 + oe];
            e2 = *(const float4*)&es[128 * tx + 64 + oe];
            e3 = *(const float4*)&es[128 * tx + 96 + oe];
            FMA4(a0, e0, 0, 0) FMA4(a0, e1, 0, 1) FMA4(a0, e2, 0, 2) FMA4(a0, e3, 0, 3)
            FMA4(a1, e0, 1, 0) FMA4(a1, e1, 1, 1) FMA4(a1, e2, 1, 2) FMA4(a1, e3, 1, 3)
            FMA4(a2, e0, 2, 0) FMA4(a2, e1, 2, 1) FMA4(a2, e2, 2, 2) FMA4(a2, e3, 2, 3)
            FMA4(a3, e0, 3, 0) FMA4(a3, e1, 3, 1) FMA4(a3, e2, 3, 2) FMA4(a3, e3, 3, 3)

            // e group 1 (codes 64+4tx+j)
            e0 = *(const float4*)&es[2048 + 128 * tx + 0  + oe];
            e1 = *(const float4*)&es[2048 + 128 * tx + 32 + oe];
            e2 = *(const float4*)&es[2048 + 128 * tx + 64 + oe];
            e3 = *(const float4*)&es[2048 + 128 * tx + 96 + oe];
            FMA4(a0, e0, 0, 4) FMA4(a0, e1, 0, 5) FMA4(a0, e2, 0, 6) FMA4(a0, e3, 0, 7)
            FMA4(a1, e0, 1, 4) FMA4(a1, e1, 1, 5) FMA4(a1, e2, 1, 6) FMA4(a1, e3, 1, 7)
            FMA4(a2, e0, 2, 4) FMA4(a2, e1, 2, 5) FMA4(a2, e2, 2, 6) FMA4(a2, e3, 2, 7)
            FMA4(a3, e0, 3, 4) FMA4(a3, e1, 3, 5) FMA4(a3, e2, 3, 6) FMA4(a3, e3, 3, 7)

            // z group 1 (tokens 64+4ty+i), e still group 1
            a0 = *(const float4*)&zs[2048 + 128 * ty + 0  + oz];
            a1 = *(const float4*)&zs[2048 + 128 * ty + 32 + oz];
            a2 = *(const float4*)&zs[2048 + 128 * ty + 64 + oz];
            a3 = *(const float4*)&zs[2048 + 128 * ty + 96 + oz];
            FMA4(a0, e0, 4, 4) FMA4(a0, e1, 4, 5) FMA4(a0, e2, 4, 6) FMA4(a0, e3, 4, 7)
            FMA4(a1, e0, 5, 4) FMA4(a1, e1, 5, 5) FMA4(a1, e2, 5, 6) FMA4(a1, e3, 5, 7)
            FMA4(a2, e0, 6, 4) FMA4(a2, e1, 6, 5) FMA4(a2, e2, 6, 6) FMA4(a2, e3, 6, 7)
            FMA4(a3, e0, 7, 4) FMA4(a3, e1, 7, 5) FMA4(a3, e2, 7, 6) FMA4(a3, e3, 7, 7)

            // e group 0 reload (cheaper than keeping 8 e-rows live)
            e0 = *(const float4*)&es[128 * tx + 0  + oe];
            e1 = *(const float4*)&es[128 * tx + 32 + oe];
            e2 = *(const float4*)&es[128 * tx + 64 + oe];
            e3 = *(const float4*)&es[128 * tx + 96 + oe];
            FMA4(a0, e0, 4, 0) FMA4(a0, e1, 4, 1) FMA4(a0, e2, 4, 2) FMA4(a0, e3, 4, 3)
            FMA4(a1, e0, 5, 0) FMA4(a1, e1, 5, 1) FMA4(a1, e2, 5, 2) FMA4(a1, e3, 5, 3)
            FMA4(a2, e0, 6, 0) FMA4(a2, e1, 6, 1) FMA4(a2, e2, 6, 2) FMA4(a2, e3, 6, 3)
            FMA4(a3, e0, 7, 0) FMA4(a3, e1, 7, 1) FMA4(a3, e2, 7, 2) FMA4(a3, e3, 7, 3)
#undef FMA4
        }
    }

    // epilogue: token norms (bit-identical, from vq_anorm), distances, first-min
    float Aval[8];
    {
        float4 v0 = *(const float4*)(wsA + t0 + 4 * ty);
        float4 v1 = *(const float4*)(wsA + t0 + 64 + 4 * ty);
        Aval[0] = v0.x; Aval[1] = v0.y; Aval[2] = v0.z; Aval[3] = v0.w;
        Aval[4] = v1.x; Aval[5] = v1.y; Aval[6] = v1.z; Aval[7] = v1.w;
    }

    float best[8];
    int   bidx[8];
#pragma unroll
    for (int i = 0; i < 8; ++i) { best[i] = __builtin_inff(); bidx[i] = 0x7fffffff; }
#pragma unroll
    for (int i = 0; i < 8; ++i)
#pragma unroll
        for (int j = 0; j < 8; ++j) {
            int cl = (j < 4) ? (4 * tx + j) : (64 + 4 * tx + (j - 4));
            float t1 = Aval[i] + Bl[cl];
            float dist = t1 - 2.0f * acc[i][j];
            if (dist < best[i]) { best[i] = dist; bidx[i] = n0 + cl; }
        }

    // lexicographic (d, idx) min over the 16 tx-threads per token
#pragma unroll
    for (int i = 0; i < 8; ++i) {
        float d = best[i]; int w = bidx[i];
        for (int off = 8; off; off >>= 1) {
            float od = __shfl_xor(d, off);
            int   ow = __shfl_xor(w, off);
            if (od < d || (od == d && ow < w)) { d = od; w = ow; }
        }
        best[i] = d; bidx[i] = w;
    }

    // merge across code-tiles: key = d_bits<<32 | idx (d>0 so bits are monotone)
    if (tx == 0) {
#pragma unroll
        for (int i = 0; i < 8; ++i) {
            int tl = (i < 4) ? (4 * ty + i) : (64 + 4 * ty + (i - 4));
            unsigned long long key =
                ((unsigned long long)__float_as_uint(best[i]) << 32) |
                (unsigned int)bidx[i];
            atomicMin(&keys[t0 + tl], key);
        }
    }
}

// ---------------- kernel 2: gather z_q, indices, fp64 loss partials.
__global__ __launch_bounds__(256) void vq_gather(const float* __restrict__ z,
                                                 const float* __restrict__ cb,
                                                 const unsigned long long* __restrict__ keys,
                                                 double* __restrict__ loss_acc,
                                                 float* __restrict__ out)
{
    __shared__ double lred[4];
    const int tid = threadIdx.x;
    const int tx = tid & 15, ty = tid >> 4;
    const int t0 = blockIdx.x * 64;

    double ld = 0.0;
#pragma unroll
    for (int i = 0; i < 4; ++i) {
        int t = t0 + ty * 4 + i;
        unsigned long long key = keys[t];
        int w = (int)(unsigned int)(key & 0xFFFFFFFFull);
        const float4* crow = (const float4*)(cb + (size_t)w * DDIM);
        const float4* zrow = (const float4*)(z + (size_t)t * DDIM);
        float4* orow = (float4*)(out + (size_t)t * DDIM);
#pragma unroll
        for (int q = 0; q < 4; ++q) {
            int c4 = tx * 4 + q;
            float4 e4 = crow[c4];
            float4 z4 = zrow[c4];
            float4 o;
            float dx;
            dx = e4.x - z4.x; o.x = z4.x + dx; ld += (double)(dx * dx);
            dx = e4.y - z4.y; o.y = z4.y + dx; ld += (double)(dx * dx);
            dx = e4.z - z4.z; o.z = z4.z + dx; ld += (double)(dx * dx);
            dx = e4.w - z4.w; o.w = z4.w + dx; ld += (double)(dx * dx);
            orow[c4] = o;
        }
        if (tx == 0) out[IDX_OFF + t] = (float)w;
    }

    for (int off = 32; off; off >>= 1) ld += __shfl_down(ld, off);
    int lane = tid & 63, wvv = tid >> 6;
    if (lane == 0) lred[wvv] = ld;
    __syncthreads();
    if (tid == 0) {
        double s = (lred[0] + lred[1]) + (lred[2] + lred[3]);
        atomicAdd(loss_acc, s);
    }
}

// ---------------- kernel 3: finalize loss = fl(mf + fl(10*mf))
__global__ void vq_finish(const double* __restrict__ loss_acc, float* __restrict__ out)
{
#pragma clang fp contract(off)
    double m = *loss_acc / 16777216.0;
    float mf = (float)m;
    float second = 10.0f * mf;
    out[LOSS_OFF] = mf + second;
}

extern "C" void kernel_launch(void* const* d_in, const int* in_sizes, int n_in,
                              void* d_out, int out_size, void* d_ws, size_t ws_size,
                              hipStream_t stream)
{
    (void)in_sizes; (void)n_in; (void)out_size; (void)ws_size;
    const float* z  = (const float*)d_in[0];
    const float* cb = (const float*)d_in[1];
    float* out = (float*)d_out;
    double* loss_acc = (double*)d_ws;                                      // 8 B
    float* wsB = (float*)((char*)d_ws + 64);                               // 4 KB
    unsigned long long* keys = (unsigned long long*)((char*)d_ws + 8192);  // 512 KB
    float* wsA = (float*)((char*)d_ws + 532480);                           // 256 KB

    vq_prep<<<dim3(64), dim3(256), 0, stream>>>(cb, wsB, loss_acc, keys);
    vq_anorm<<<dim3(NTOK / 256), dim3(256), 0, stream>>>(z, wsA);
    vq_main<<<dim3(4096), dim3(256), 0, stream>>>(z, cb, wsB, wsA, keys);
    vq_gather<<<dim3(NTOK / 64), dim3(256), 0, stream>>>(z, cb, keys, loss_acc, out);
    vq_finish<<<dim3(1), dim3(1), 0, stream>>>(loss_acc, out);
}